// Round 11
// baseline (189.000 us; speedup 1.0000x reference)
//
#include <hip/hip_runtime.h>
#include <hip/hip_bf16.h>

// Problem constants (EmbDotSoftMax): B=4096, N_CITY=50, EC=128, VOCAB=40000
#define NC    50
#define EC    128
#define VOCAB 40000

// ---------------- Kernel 0: pack W^T into ws (once per call, ~2us) ----------------
// WTpack[k4*128 + e] = float4{ W[e][4k4+0..3] } -> GEMV reads coalesced over e.
__global__ __launch_bounds__(256)
void EmbDotSoftMax_wtpack_kernel(const float* __restrict__ W,
                                 float4*      __restrict__ WTp)
{
    const int t = threadIdx.x;
    #pragma unroll
    for (int idx = t; idx < (EC / 4) * EC; idx += 256) {
        const int k4 = idx >> 7;     // 0..31
        const int e  = idx & 127;    // 0..127
        WTp[idx] = reinterpret_cast<const float4*>(W)[e * (EC / 4) + k4];
    }
}

// ---------------- Kernel 1: fully fused, fill-first ----------------
// One block per row, 128 threads.
//  1. Issue the row's 1e-6 fill stores FIRST (store stream saturates from
//     t=0; acks return at L2 speed so later barriers don't stall on HBM).
//  2. Compute (zero-shuffle GEMV via WTp, zero-shuffle scores, softmax)
//     overlaps the fill drain.
//  3. Final barrier, then plain-store p_sum + 1e-6 from owner lanes
//     (duplicates combined in LDS — no atomics, no RMW traffic).
__global__ __launch_bounds__(128)
void EmbDotSoftMax_fused_kernel(const float*  __restrict__ x,
                                const float*  __restrict__ emb,
                                const int*    __restrict__ ids,
                                const float4* __restrict__ WTp,
                                const float*  __restrict__ bias,
                                float*        __restrict__ out)
{
    const int b   = blockIdx.x;
    const int tid = threadIdx.x;

    __shared__ float4 x_s4[EC / 4];
    __shared__ float  pred_s[EC];
    __shared__ float  score_s[NC];
    __shared__ float  p_s[NC];
    __shared__ int    id_s[NC];

    float* out_row = out + (size_t)b * VOCAB;

    // ---- 1. fill own row with 1e-6 (fire-and-forget float4 stores) ----
    {
        const float4 fv = make_float4(1e-6f, 1e-6f, 1e-6f, 1e-6f);
        float4* out4 = reinterpret_cast<float4*>(out_row);   // VOCAB%4==0
        for (int i = tid; i < VOCAB / 4; i += 128)
            out4[i] = fv;
    }

    // ---- 2. stage x and ids ----
    if (tid < EC / 4)
        x_s4[tid] = reinterpret_cast<const float4*>(x + (size_t)b * EC)[tid];
    if (tid < NC)
        id_s[tid] = ids[(size_t)b * NC + tid];
    __syncthreads();

    // ---- 3. GEMV: pred[t] = dot(W[t,:], x) + bias[t] (coalesced WTp) ----
    {
        float acc = 0.0f;
        #pragma unroll
        for (int k4 = 0; k4 < EC / 4; ++k4) {
            const float4 w  = WTp[k4 * EC + tid];   // coalesced, L2-hot
            const float4 xv = x_s4[k4];             // LDS broadcast
            acc = fmaf(w.x, xv.x, acc);
            acc = fmaf(w.y, xv.y, acc);
            acc = fmaf(w.z, xv.z, acc);
            acc = fmaf(w.w, xv.w, acc);
        }
        pred_s[tid] = acc + bias[tid];
    }
    __syncthreads();

    // ---- 4. scores: wave w, lane l<25 owns city n = w*25+l ----
    {
        const int w = tid >> 6;
        const int l = tid & 63;
        if (l < NC / 2) {
            const int n = w * (NC / 2) + l;
            const float4* er =
                reinterpret_cast<const float4*>(emb + ((size_t)b * NC + n) * EC);
            float acc = 0.0f;
            #pragma unroll
            for (int j = 0; j < EC / 4; ++j) {
                const float4 e4 = er[j];
                const float4 p4 = reinterpret_cast<const float4*>(pred_s)[j];
                acc = fmaf(e4.x, p4.x, acc);
                acc = fmaf(e4.y, p4.y, acc);
                acc = fmaf(e4.z, p4.z, acc);
                acc = fmaf(e4.w, p4.w, acc);
            }
            score_s[n] = acc;
        }
    }
    __syncthreads();

    // ---- 5. softmax over 50 ----
    if (tid < NC) {
        float m = -1e30f;
        #pragma unroll
        for (int n = 0; n < NC; ++n) m = fmaxf(m, score_s[n]);
        float sum = 0.0f;
        #pragma unroll
        for (int n = 0; n < NC; ++n) sum += __expf(score_s[n] - m);
        p_s[tid] = __expf(score_s[tid] - m) / sum;
    }
    __syncthreads();   // also guarantees all fill stores retired (vmcnt drain)

    // ---- 6. owner lanes combine duplicates and plain-store p_sum + 1e-6 ----
    if (tid < NC) {
        const int myid = id_s[tid];
        int   first = -1;
        float s     = 0.0f;
        #pragma unroll
        for (int j = 0; j < NC; ++j) {
            if (id_s[j] == myid) {
                if (first < 0) first = j;
                s += p_s[j];
            }
        }
        if (first == tid)
            out_row[myid] = s + 1e-6f;
    }
}

// ---------------- Fallback (ws too small): memset + shuffle scatter ----------------
__global__ __launch_bounds__(128)
void EmbDotSoftMax_scatter_fb(const float* __restrict__ x,
                              const float* __restrict__ emb,
                              const int*   __restrict__ ids,
                              const float* __restrict__ W,
                              const float* __restrict__ bias,
                              float*       __restrict__ out)
{
    const int b   = blockIdx.x;
    const int tid = threadIdx.x;
    const int w   = tid >> 6;
    const int l   = tid & 63;
    __shared__ float pred_s[EC];
    __shared__ float scores_s[NC];
    float* out_row = out + (size_t)b * VOCAB;
    {
        const float x0 = x[(size_t)b * EC + l];
        const float x1 = x[(size_t)b * EC + 64 + l];
        const float* Wbase = W + (size_t)w * 64 * EC;
        float mine = 0.0f;
        #pragma unroll 8
        for (int i = 0; i < 64; ++i) {
            const float* row = Wbase + i * EC;
            float part = fmaf(x0, row[l], x1 * row[l + 64]);
            #pragma unroll
            for (int off = 32; off; off >>= 1)
                part += __shfl_xor(part, off);
            if (i == l) mine = part;
        }
        pred_s[w * 64 + l] = mine + bias[w * 64 + l];
    }
    __syncthreads();
    {
        const float p0 = pred_s[l];
        const float p1 = pred_s[l + 64];
        const float* base = emb + (size_t)b * NC * EC + (size_t)w * (NC / 2) * EC;
        float part[NC / 2];
        #pragma unroll
        for (int i = 0; i < NC / 2; ++i) {
            const float* er = base + i * EC;
            part[i] = fmaf(p0, er[l], p1 * er[l + 64]);
        }
        #pragma unroll
        for (int off = 32; off; off >>= 1) {
            #pragma unroll
            for (int i = 0; i < NC / 2; ++i)
                part[i] += __shfl_xor(part[i], off);
        }
        if (l == 0) {
            #pragma unroll
            for (int i = 0; i < NC / 2; ++i)
                scores_s[w * (NC / 2) + i] = part[i];
        }
    }
    __syncthreads();
    if (tid < NC) {
        float m = -1e30f;
        #pragma unroll
        for (int n = 0; n < NC; ++n) m = fmaxf(m, scores_s[n]);
        float sum = 0.0f;
        #pragma unroll
        for (int n = 0; n < NC; ++n) sum += __expf(scores_s[n] - m);
        const float p = __expf(scores_s[tid] - m) / sum;
        atomicAdd(out_row + ids[(size_t)b * NC + tid], p);
    }
}

extern "C" void kernel_launch(void* const* d_in, const int* in_sizes, int n_in,
                              void* d_out, int out_size, void* d_ws, size_t ws_size,
                              hipStream_t stream) {
    const float* x    = (const float*)d_in[0];
    const float* emb  = (const float*)d_in[1];
    const int*   ids  = (const int*)d_in[2];
    // d_in[3] = prob (zeros) — unused
    const float* W    = (const float*)d_in[4];
    const float* bias = (const float*)d_in[5];
    float*       out  = (float*)d_out;

    const int B = in_sizes[0] / EC;    // 4096
    const size_t ws_needed = (size_t)(EC / 4) * EC * sizeof(float4);  // 64 KB

    if (ws_size >= ws_needed) {
        float4* WTp = (float4*)d_ws;
        hipLaunchKernelGGL(EmbDotSoftMax_wtpack_kernel,
                           dim3(1), dim3(256), 0, stream, W, WTp);
        hipLaunchKernelGGL(EmbDotSoftMax_fused_kernel,
                           dim3(B), dim3(128), 0, stream,
                           x, emb, ids, WTp, bias, out);
    } else {
        hipMemsetAsync(d_out, 0, (size_t)out_size * sizeof(float), stream);
        hipLaunchKernelGGL(EmbDotSoftMax_scatter_fb,
                           dim3(B), dim3(128), 0, stream,
                           x, emb, ids, W, bias, out);
    }
}